// Round 4
// baseline (447.320 us; speedup 1.0000x reference)
//
#include <hip/hip_runtime.h>

// Geometry (fixed by reference)
#define NTOK 197
#define NHEADS 12
#define DIM 768
#define PP 20
#define KK 5
#define STOT 397
#define BB 128
#define NIMG 196
#define NIMGBLK 392              // 392*64 = 25088 image tokens
#define NBLK 394                 // + 2 cls blocks (128 cls tokens)
#define CHUNK 128
#define NCHUNK 6
#define PITCH 132                // floats; rows 16B-aligned (132*4 = 33*16)
#define HSTRIDE (NTOK * STOT)    // 78209
#define NALLTOK (BB * NTOK)      // 25216

static const long long MASK_ELEMS = (long long)BB * NHEADS * NTOK * STOT; // 120129024

typedef float float4b __attribute__((ext_vector_type(4), aligned(16)));

// ---------------- Kernel 1: inverse norms of the 40 keys at `layer` -------------
__global__ void knorm_kernel(const float* __restrict__ kc,
                             const float* __restrict__ ki,
                             const int* __restrict__ layer_p,
                             float* __restrict__ invn /*40 floats*/) {
    int layer = *layer_p;
    int kid = blockIdx.x;              // 0..39 ; 0-19 cls, 20-39 img
    const float* base = (kid < PP ? kc : ki) + (size_t)layer * PP * DIM;
    const float* kp = base + (size_t)(kid % PP) * DIM;
    int lane = threadIdx.x;            // 64 threads
    float s = 0.f;
    for (int i = lane; i < DIM; i += 64) { float v = kp[i]; s += v * v; }
    #pragma unroll
    for (int m = 1; m < 64; m <<= 1) s += __shfl_xor(s, m, 64);
    if (lane == 0) invn[kid] = 1.0f / fmaxf(sqrtf(s), 1e-12f);
}

// ---------------- Kernel 2: routing (token-per-lane, LDS-staged x) --------------
// 394 blocks x 64 threads. Blocks 0..391: image tokens; 392..393: cls tokens.
__global__ __launch_bounds__(64) void route_kernel(
        const float* __restrict__ x,
        const float* __restrict__ kc,
        const float* __restrict__ ki,
        const int* __restrict__ layer_p,
        const float* __restrict__ invn,
        int* __restrict__ bits_ws,      /* [25216] */
        float* __restrict__ dist_part   /* [394]   */) {
    const int blk = blockIdx.x;
    const int lane = threadIdx.x;      // 0..63
    const bool is_cls = (blk >= NIMGBLK);
    const int layer = __builtin_amdgcn_readfirstlane(*layer_p);

    __shared__ float xs[64 * PITCH];   // 33,792 B
    __shared__ int rowoff[64];

    int tok;
    if (!is_cls) {
        int i = blk * 64 + lane;                   // 0..25087
        int b = i / NIMG;
        int t = i - b * NIMG;                      // 0..195
        tok = b * NTOK + 1 + t;
    } else {
        int b = (blk - NIMGBLK) * 64 + lane;       // 0..127
        tok = b * NTOK;
    }
    rowoff[lane] = tok * DIM;
    const float* __restrict__ kb = (is_cls ? kc : ki) + (size_t)layer * PP * DIM;
    const float* __restrict__ ik = invn + (is_cls ? 0 : PP);
    __syncthreads();

    float acc[PP];
    #pragma unroll
    for (int p = 0; p < PP; ++p) acc[p] = 0.f;
    float xsq = 0.f;

    for (int c = 0; c < NCHUNK; ++c) {
        // stage x chunk: 64 rows x 32 float4, coalesced (512B runs per row)
        #pragma unroll 8
        for (int pass = 0; pass < 32; ++pass) {
            int idx = pass * 64 + lane;
            int r = idx >> 5, f4 = idx & 31;
            float4b v = *(const float4b*)(x + rowoff[r] + c * CHUNK + f4 * 4);
            *(float4b*)&xs[r * PITCH + f4 * 4] = v;
        }
        __syncthreads();
        // compute: lane owns one token; keys via wave-uniform global (s_load)
        #pragma unroll 4
        for (int q = 0; q < 32; ++q) {
            float4b xv = *(const float4b*)&xs[lane * PITCH + q * 4];
            xsq += xv.x * xv.x + xv.y * xv.y + xv.z * xv.z + xv.w * xv.w;
            #pragma unroll
            for (int p = 0; p < PP; ++p) {
                float4b kv = *(const float4b*)(kb + p * DIM + c * CHUNK + q * 4);
                acc[p] += xv.x * kv.x + xv.y * kv.y + xv.z * kv.z + xv.w * kv.w;
            }
        }
        __syncthreads();
    }

    // sims + private top-5 (shuffle-free)
    float invx = 1.0f / fmaxf(sqrtf(xsq), 1e-12f);
    float sims[PP];
    #pragma unroll
    for (int p = 0; p < PP; ++p) sims[p] = acc[p] * invx * ik[p];
    int bits = 0; float sum5 = 0.f;
    #pragma unroll
    for (int j = 0; j < KK; ++j) {
        int bi = 0; float bv = -3.0e38f;
        #pragma unroll
        for (int p = 0; p < PP; ++p) {
            bool ok = !((bits >> p) & 1) && (sims[p] > bv);
            bv = ok ? sims[p] : bv;
            bi = ok ? p : bi;
        }
        bits |= (1 << bi);
        sum5 += bv;
    }
    bits_ws[tok] = bits;

    float dist = (float)KK - sum5;
    #pragma unroll
    for (int m = 1; m < 64; m <<= 1) dist += __shfl_xor(dist, m, 64);
    if (lane == 0) dist_part[blk] = dist;
}

// ---------------- Kernel 3: massively-parallel streaming mask writer ------------
// 25216 blocks x 256 threads, one block per (b,t). Columns s>=256 are always 1.
__global__ __launch_bounds__(256) void write_kernel(
        const int* __restrict__ bits_ws,
        float* __restrict__ out) {
    const int bid = blockIdx.x;          // 0..25215
    const int tid = threadIdx.x;         // 0..255 == column s1
    const int b = bid / NTOK;
    const int t = bid - b * NTOK;
    const int bits = bits_ws[bid];       // uniform -> scalar load
    const int lo = (t == 0) ? 1 : 101;   // routing window start

    // v1 for s = tid (0..255)
    unsigned u = (unsigned)(tid - lo);   // wraps if tid < lo
    int q = (int)(u / 5u);
    bool inw = u < 100u;
    bool one = (tid == 0) | (tid >= 201);
    float v1 = one ? 1.f : (inw ? (float)((bits >> q) & 1) : 0.f);
    // s2 = tid + 256 is always >= 201 -> always 1.0
    const int s2 = tid + 256;

    float* base = out + ((size_t)(b * NHEADS) * NTOK + t) * (size_t)STOT;
    #pragma unroll
    for (int h = 0; h < NHEADS; ++h) {
        float* dst = base + (size_t)h * HSTRIDE;
        dst[tid] = v1;
        if (s2 < STOT) dst[s2] = 1.0f;
    }
}

// ---------------- Kernel 4: tiny final dist reduce ------------------------------
__global__ void reduce_kernel(const float* __restrict__ dist_part,
                              float* __restrict__ out) {
    int lane = threadIdx.x;            // 64
    float si = 0.f, sc = 0.f;
    for (int i = lane; i < NIMGBLK; i += 64) si += dist_part[i];
    if (lane < 2) sc = dist_part[NIMGBLK + lane];
    #pragma unroll
    for (int m = 1; m < 64; m <<= 1) {
        si += __shfl_xor(si, m, 64);
        sc += __shfl_xor(sc, m, 64);
    }
    if (lane == 0)
        out[MASK_ELEMS] = sc * (1.0f / (BB * KK)) + si * (1.0f / (BB * NIMG * KK));
}

// ---------------- launcher ------------------------------------------------------
extern "C" void kernel_launch(void* const* d_in, const int* in_sizes, int n_in,
                              void* d_out, int out_size, void* d_ws, size_t ws_size,
                              hipStream_t stream) {
    const float* x  = (const float*)d_in[0];
    const float* kc = (const float*)d_in[1];
    const float* ki = (const float*)d_in[2];
    const int* layer = (const int*)d_in[3];
    float* out = (float*)d_out;

    // ws: [0..64) invnorms, [64..64+25216) bits, then [ .. +394) dist partials
    float* invn   = (float*)d_ws;
    int*   bitsws = (int*)d_ws + 64;
    float* dpart  = (float*)d_ws + 64 + NALLTOK;

    knorm_kernel<<<40, 64, 0, stream>>>(kc, ki, layer, invn);
    route_kernel<<<NBLK, 64, 0, stream>>>(x, kc, ki, layer, invn, bitsws, dpart);
    write_kernel<<<NALLTOK, 256, 0, stream>>>(bitsws, out);
    reduce_kernel<<<1, 64, 0, stream>>>(dpart, out);
}

// Round 5
// 243.751 us; speedup vs baseline: 1.8352x; 1.8352x over previous
//
#include <hip/hip_runtime.h>

// Geometry (fixed by reference)
#define NTOK 197
#define NHEADS 12
#define DIM 768
#define PP 20
#define KK 5
#define STOT 397
#define BB 128
#define NIMG 196
#define NIMGBLK 392              // 392*64 = 25088 image tokens
#define NBLK 394                 // + 2 cls blocks (128 cls tokens)
#define CHUNK 128
#define NCHUNK 6
#define PITCH 132                // floats; rows 16B-aligned (132*4 = 33*16)
#define HSTRIDE (NTOK * STOT)    // 78209
#define NALLTOK (BB * NTOK)      // 25216

static const long long MASK_ELEMS = (long long)BB * NHEADS * NTOK * STOT; // 120129024

typedef float float4a __attribute__((ext_vector_type(4), aligned(4)));   // maybe-unaligned
typedef float float4b __attribute__((ext_vector_type(4), aligned(16)));  // known-aligned

// ---------------- Kernel 1: inverse norms of the 40 keys at `layer` -------------
__global__ void knorm_kernel(const float* __restrict__ kc,
                             const float* __restrict__ ki,
                             const int* __restrict__ layer_p,
                             float* __restrict__ invn /*40 floats*/) {
    int layer = *layer_p;
    int kid = blockIdx.x;              // 0..39 ; 0-19 cls, 20-39 img
    const float* base = (kid < PP ? kc : ki) + (size_t)layer * PP * DIM;
    const float* kp = base + (size_t)(kid % PP) * DIM;
    int lane = threadIdx.x;            // 64 threads
    float s = 0.f;
    for (int i = lane; i < DIM; i += 64) { float v = kp[i]; s += v * v; }
    #pragma unroll
    for (int m = 1; m < 64; m <<= 1) s += __shfl_xor(s, m, 64);
    if (lane == 0) invn[kid] = 1.0f / fmaxf(sqrtf(s), 1e-12f);
}

// ---------------- Kernel 2: routing (token-per-lane, LDS-staged x AND keys) -----
// 394 blocks x 64 threads. Blocks 0..391: image tokens; 392..393: cls tokens.
// This is R3's proven compute structure (keys read from LDS as uniform
// broadcasts, NOT uniform global loads — those stay vector loads and stall).
__global__ __launch_bounds__(64) void route_kernel(
        const float* __restrict__ x,
        const float* __restrict__ kc,
        const float* __restrict__ ki,
        const int* __restrict__ layer_p,
        const float* __restrict__ invn,
        int* __restrict__ bits_ws,      /* [25216] */
        float* __restrict__ dist_part   /* [394]   */) {
    const int blk = blockIdx.x;
    const int lane = threadIdx.x;      // 0..63
    const bool is_cls = (blk >= NIMGBLK);
    const int layer = *layer_p;

    __shared__ float xs[64 * PITCH];   // 33,792 B
    __shared__ float ks[PP * PITCH];   // 10,560 B
    __shared__ int rowoff[64];

    int tok;
    if (!is_cls) {
        int i = blk * 64 + lane;                   // 0..25087
        int b = i / NIMG;
        int t = i - b * NIMG;                      // 0..195
        tok = b * NTOK + 1 + t;
    } else {
        int b = (blk - NIMGBLK) * 64 + lane;       // 0..127
        tok = b * NTOK;
    }
    rowoff[lane] = tok * DIM;
    const float* __restrict__ kb = (is_cls ? kc : ki) + (size_t)layer * PP * DIM;
    const float* __restrict__ ik = invn + (is_cls ? 0 : PP);
    __syncthreads();

    float acc[PP];
    #pragma unroll
    for (int p = 0; p < PP; ++p) acc[p] = 0.f;
    float xsq = 0.f;

    for (int c = 0; c < NCHUNK; ++c) {
        // stage keys chunk: 20 rows x 32 float4, coalesced
        #pragma unroll
        for (int pass = 0; pass < 10; ++pass) {
            int idx = pass * 64 + lane;            // 0..639
            int kr = idx >> 5, f4 = idx & 31;
            float4b v = *(const float4b*)(kb + kr * DIM + c * CHUNK + f4 * 4);
            *(float4b*)&ks[kr * PITCH + f4 * 4] = v;
        }
        // stage x chunk: 64 rows x 32 float4, coalesced (512B runs per row)
        #pragma unroll 8
        for (int pass = 0; pass < 32; ++pass) {
            int idx = pass * 64 + lane;
            int r = idx >> 5, f4 = idx & 31;
            float4b v = *(const float4b*)(x + rowoff[r] + c * CHUNK + f4 * 4);
            *(float4b*)&xs[r * PITCH + f4 * 4] = v;
        }
        __syncthreads();
        // compute: lane owns one token; key reads are uniform LDS broadcasts
        #pragma unroll 2
        for (int q = 0; q < 32; ++q) {
            float4b xv = *(const float4b*)&xs[lane * PITCH + q * 4];
            xsq += xv.x * xv.x + xv.y * xv.y + xv.z * xv.z + xv.w * xv.w;
            #pragma unroll
            for (int p = 0; p < PP; ++p) {
                float4b kv = *(const float4b*)&ks[p * PITCH + q * 4];
                acc[p] += xv.x * kv.x + xv.y * kv.y + xv.z * kv.z + xv.w * kv.w;
            }
        }
        __syncthreads();
    }

    // sims + private top-5 (shuffle-free)
    float invx = 1.0f / fmaxf(sqrtf(xsq), 1e-12f);
    float sims[PP];
    #pragma unroll
    for (int p = 0; p < PP; ++p) sims[p] = acc[p] * invx * ik[p];
    int bits = 0; float sum5 = 0.f;
    #pragma unroll
    for (int j = 0; j < KK; ++j) {
        int bi = 0; float bv = -3.0e38f;
        #pragma unroll
        for (int p = 0; p < PP; ++p) {
            bool ok = !((bits >> p) & 1) && (sims[p] > bv);
            bv = ok ? sims[p] : bv;
            bi = ok ? p : bi;
        }
        bits |= (1 << bi);
        sum5 += bv;
    }
    bits_ws[tok] = bits;

    float dist = (float)KK - sum5;
    #pragma unroll
    for (int m = 1; m < 64; m <<= 1) dist += __shfl_xor(dist, m, 64);
    if (lane == 0) dist_part[blk] = dist;
}

// ---------------- Kernel 3: streaming mask writer (R1 structure) ----------------
// 25216 blocks x 256 threads, one block per (b,t): build 397-float row in LDS,
// stream it to all 12 heads with vec4 nontemporal stores.
__global__ __launch_bounds__(256) void write_kernel(
        const int* __restrict__ bits_ws,
        float* __restrict__ out) {
    const int bid = blockIdx.x;          // 0..25215
    const int tid = threadIdx.x;
    const int b = bid / NTOK;
    const int t = bid - b * NTOK;
    const int bits = bits_ws[bid];       // uniform per block
    const int lo = (t == 0) ? 1 : 101;   // routing-window start

    __shared__ __align__(16) float row[STOT + 3];
    for (int s = tid; s < STOT; s += 256) {
        unsigned u = (unsigned)(s - lo);
        bool inw = u < 100u;
        int q = (int)(u / 5u);
        bool one = (s == 0) | (s >= 201);
        row[s] = one ? 1.f : (inw ? (float)((bits >> q) & 1) : 0.f);
    }
    __syncthreads();

    // 6 passes x 2 heads; 128 threads per head-row (99 vec4 writers + 1 tail)
    const int hl = tid >> 7;          // 0..1
    const int j  = tid & 127;         // 0..127
    float* base = out + ((size_t)(b * NHEADS) * NTOK + t) * (size_t)STOT;
    #pragma unroll
    for (int pass = 0; pass < 6; ++pass) {
        float* dst = base + (size_t)(pass * 2 + hl) * HSTRIDE;
        if (j < 99) {
            float4a v = *(const float4a*)&row[4 * j];
            __builtin_nontemporal_store(v, (float4a*)(dst + 4 * j));
        } else if (j == 99) {
            __builtin_nontemporal_store(row[396], dst + 396);
        }
    }
}

// ---------------- Kernel 4: tiny final dist reduce ------------------------------
__global__ void reduce_kernel(const float* __restrict__ dist_part,
                              float* __restrict__ out) {
    int lane = threadIdx.x;            // 64
    float si = 0.f, sc = 0.f;
    for (int i = lane; i < NIMGBLK; i += 64) si += dist_part[i];
    if (lane < 2) sc = dist_part[NIMGBLK + lane];
    #pragma unroll
    for (int m = 1; m < 64; m <<= 1) {
        si += __shfl_xor(si, m, 64);
        sc += __shfl_xor(sc, m, 64);
    }
    if (lane == 0)
        out[MASK_ELEMS] = sc * (1.0f / (BB * KK)) + si * (1.0f / (BB * NIMG * KK));
}

// ---------------- launcher ------------------------------------------------------
extern "C" void kernel_launch(void* const* d_in, const int* in_sizes, int n_in,
                              void* d_out, int out_size, void* d_ws, size_t ws_size,
                              hipStream_t stream) {
    const float* x  = (const float*)d_in[0];
    const float* kc = (const float*)d_in[1];
    const float* ki = (const float*)d_in[2];
    const int* layer = (const int*)d_in[3];
    float* out = (float*)d_out;

    // ws: [0..64) invnorms, [64..64+25216) bits, then [.. +394) dist partials
    float* invn   = (float*)d_ws;
    int*   bitsws = (int*)d_ws + 64;
    float* dpart  = (float*)d_ws + 64 + NALLTOK;

    knorm_kernel<<<40, 64, 0, stream>>>(kc, ki, layer, invn);
    route_kernel<<<NBLK, 64, 0, stream>>>(x, kc, ki, layer, invn, bitsws, dpart);
    write_kernel<<<NALLTOK, 256, 0, stream>>>(bitsws, out);
    reduce_kernel<<<1, 64, 0, stream>>>(dpart, out);
}